// Round 9
// baseline (327.135 us; speedup 1.0000x reference)
//
#include <hip/hip_runtime.h>
#include <stdint.h>

#define EPSL 1e-11f

typedef _Float16 h2 __attribute__((ext_vector_type(2)));
typedef _Float16 h8 __attribute__((ext_vector_type(8)));
typedef __attribute__((ext_vector_type(4))) float f32x4;
typedef __attribute__((ext_vector_type(16))) float f32x16;

// ---------------- helpers ----------------
__device__ __forceinline__ uint32_t pk2h(float a, float b) {
    union { h2 h; uint32_t u; } t;
    t.h = (h2){ (_Float16)a, (_Float16)b };
    return t.u;
}
__device__ __forceinline__ uint16_t f2h(float a) {
    union { _Float16 h; uint16_t u; } t; t.h = (_Float16)a; return t.u;
}

__device__ __forceinline__ uint64_t sm64(uint64_t x) {
    x += 0x9E3779B97F4A7C15ULL;
    x = (x ^ (x >> 30)) * 0xBF58476D1CE4E5B9ULL;
    x = (x ^ (x >> 27)) * 0x94D049BB133111EBULL;
    return x ^ (x >> 31);
}

__device__ __forceinline__ uint32_t rowz_of(uint32_t f, int dim, int S, int s) {
    uint32_t b = f & 31u;
    uint32_t r = f >> 5;
    uint32_t d, h, w;
    if (dim == 0) {
        w = r & 7u; h = (r >> 3) & 7u; d = (r >> 6) + (uint32_t)s;
    } else if (dim == 1) {
        w = r & 7u; uint32_t q = r >> 3;
        h = q % (uint32_t)S + (uint32_t)s; d = q / (uint32_t)S;
    } else {
        w = r % (uint32_t)S + (uint32_t)s; uint32_t q = r / (uint32_t)S;
        h = q & 7u; d = q >> 3;
    }
    return b * 512u + d * 64u + h * 8u + w;
}

// ---------------- kernels ----------------
__global__ void k_init(float* sums_s, int* cnts_s) {
    int t = blockIdx.x * 256 + threadIdx.x;
    if (t < 1152) { sums_s[t] = 0.f; cnts_s[t] = 0; }
}

// Transpose+cast to fp16, ROW-MAJOR [row=b*512+p][ch] for both z and c.
__global__ __launch_bounds__(256) void k_prep(const float* __restrict__ z,
                                              const float* __restrict__ c,
                                              uint16_t* __restrict__ zh,
                                              uint16_t* __restrict__ cTh) {
    __shared__ float tile[32][65];
    const int t = threadIdx.x;
    const int b = blockIdx.z & 31, isC = blockIdx.z >> 5;
    const float* src = (isC ? c : z) + (size_t)b * 131072;
    const int p0 = blockIdx.x * 64, ch0 = blockIdx.y * 32;
    const int pl = t & 63, cl0 = t >> 6;
    #pragma unroll
    for (int i = 0; i < 8; i++)
        tile[cl0 + i * 4][pl] = src[(ch0 + cl0 + i * 4) * 512 + p0 + pl];
    __syncthreads();
    const int ml = t >> 2, ck = (t & 3) * 8;
    uint4 o;
    o.x = pk2h(tile[ck + 0][ml], tile[ck + 1][ml]);
    o.y = pk2h(tile[ck + 2][ml], tile[ck + 3][ml]);
    o.z = pk2h(tile[ck + 4][ml], tile[ck + 5][ml]);
    o.w = pk2h(tile[ck + 6][ml], tile[ck + 7][ml]);
    uint16_t* dst = isC ? cTh : zh;
    *(uint4*)(dst + (size_t)(b * 512 + p0 + ml) * 256 + ch0 + ck) = o;
}

// W [kk][o][c] f32 -> Whf fp16, 32x32x16 B-fragment order
__global__ __launch_bounds__(256) void k_castw(const float* __restrict__ W,
                                               uint16_t* __restrict__ Whf) {
    const int gid = blockIdx.x * 4 + (threadIdx.x >> 6);
    const int lane = threadIdx.x & 63;
    const int kk = gid >> 7, rem = gid & 127;
    const int ks2 = rem >> 3, ot = rem & 7;
    const int o = ot * 32 + (lane & 31);
    const int cc = ks2 * 16 + (lane >> 5) * 8;
    const float* src = W + ((size_t)kk * 256 + o) * 256 + cc;
    float4 v0 = *(const float4*)src;
    float4 v1 = *(const float4*)(src + 4);
    uint4 out = make_uint4(pk2h(v0.x, v0.y), pk2h(v0.z, v0.w),
                           pk2h(v1.x, v1.y), pk2h(v1.z, v1.w));
    *(uint4*)(Whf + (size_t)gid * 512 + lane * 8) = out;
}

// ZWh[kk][m][o] via 32x32x16 MFMA (unchanged from round 7)
__global__ __launch_bounds__(256, 2) void k_gemm(const uint16_t* __restrict__ zh,
                                                 const uint16_t* __restrict__ Whf,
                                                 uint16_t* __restrict__ ZWh) {
    __shared__ uint16_t Bbuf[2][4096];
    __shared__ uint16_t Cbuf[4][4096];
    const int kk = blockIdx.y;
    const int t = threadIdx.x, lane = t & 63, wv = t >> 6;
    const int m0 = blockIdx.x * 128 + wv * 32;
    const int col = lane & 31, hl = lane >> 5;
    const uint16_t* W32 = Whf + (size_t)kk * 65536;
    const uint16_t* A0 = zh + (size_t)(m0 + col) * 256 + hl * 8;

    f32x16 acc[8];
    #pragma unroll
    for (int i = 0; i < 8; i++)
        #pragma unroll
        for (int jj = 0; jj < 16; jj++) acc[i][jj] = 0.f;

    {
        const uint16_t* src = W32 + t * 16;
        *(uint4*)(&Bbuf[0][t * 16]) = *(const uint4*)src;
        *(uint4*)(&Bbuf[0][t * 16 + 8]) = *(const uint4*)(src + 8);
    }
    __syncthreads();
    for (int ks2 = 0; ks2 < 16; ks2++) {
        if (ks2 < 15) {
            const uint16_t* src = W32 + (size_t)(ks2 + 1) * 4096 + t * 16;
            uint16_t* db = Bbuf[(ks2 + 1) & 1];
            *(uint4*)(&db[t * 16]) = *(const uint4*)src;
            *(uint4*)(&db[t * 16 + 8]) = *(const uint4*)(src + 8);
        }
        h8 a = *(const h8*)(A0 + ks2 * 16);
        const uint16_t* Bb = Bbuf[ks2 & 1];
        #pragma unroll
        for (int ot = 0; ot < 8; ot++) {
            h8 bv = *(const h8*)(&Bb[ot * 512 + lane * 8]);
            acc[ot] = __builtin_amdgcn_mfma_f32_32x32x16_f16(a, bv, acc[ot], 0, 0, 0);
        }
        __syncthreads();
    }

    uint16_t* Lb = Cbuf[wv];
    uint16_t* dstbase = ZWh + ((size_t)kk * 16384 + m0) * 256;
    #pragma unroll
    for (int hh = 0; hh < 2; hh++) {
        #pragma unroll
        for (int ot = 0; ot < 8; ot++)
            #pragma unroll
            for (int rg = 0; rg < 8; rg++) {
                int reg = hh * 8 + rg;
                int row = (reg & 3) + 8 * (reg >> 2) + 4 * hl;
                Lb[(row - hh * 16) * 256 + ot * 32 + col] = f2h(acc[ot][reg]);
            }
        const uint4* Lr = (const uint4*)Lb;
        uint4* dst = (uint4*)(dstbase + hh * 16 * 256);
        #pragma unroll
        for (int i = 0; i < 8; i++)
            dst[i * 64 + lane] = Lr[i * 64 + lane];
    }
}

// Score v9: segment-minimal staging. One wave = 16 positions (same b,
// consecutive r). 10 staged "sets" of 16 rows each: set0=ctx, set1=pos,
// sets 2..9 = negative sets (positions 2j,2j+1 use neg set j).
// Global loads: inst i covers rows 2i,2i+1 full-width (2 segments/inst).
// XOR bank swizzle chunk^(row&7) applied on the global side. Single 8 KB
// LDS buffer per wave (in-order LDS), depth-2 register prefetch.
__global__ __launch_bounds__(256, 3) void k_score(const uint16_t* __restrict__ ZWh,
                                                  const uint16_t* __restrict__ cTh,
                                                  const int* __restrict__ ign,
                                                  float* sums_s, int* cnts_s) {
    __shared__ uint16_t nbuf[4][4096];      // 4 waves x 8 KB
    __shared__ float sbuf[4][288];
    __shared__ float wsum[4], wcnt[4];
    int bid = blockIdx.x;
    int kk = 0, cum = 0;
    for (;;) { int nb = 96 * (6 - kk); if (bid < cum + nb) break; cum += nb; kk++; }
    const int S = 6 - kk, T = S * 2048, s = kk + 2;
    const uint16_t* ZW = ZWh + (size_t)kk * 16384 * 256;

    const int local = bid - cum;
    const int dim = local / (32 * S);
    const int loc2 = local - dim * 32 * S;
    const int term = dim * 6 + kk;

    const int t = threadIdx.x, lane = t & 63, wv = t >> 6;
    const int lm = lane & 15, lq = lane >> 4;
    const uint32_t gidx = (uint32_t)(loc2 * 4 + wv);
    const uint32_t b = gidx & 31u;
    const uint32_t rb = gidx >> 5;
    const uint32_t r = rb * 16u + (uint32_t)lm;   // row slot lm's position

    uint32_t d, h, w;
    if (dim == 0)      { w = r & 7u; h = (r >> 3) & 7u; d = r >> 6; }
    else if (dim == 1) { w = r & 7u; uint32_t qq = r >> 3; h = qq % (uint32_t)S; d = qq / (uint32_t)S; }
    else               { w = r % (uint32_t)S; uint32_t qq = r / (uint32_t)S; h = qq & 7u; d = qq >> 3; }
    uint32_t pc = d * 64u + h * 8u + w;
    uint32_t pz = pc + (dim == 0 ? (uint32_t)s * 64u : dim == 1 ? (uint32_t)s * 8u : (uint32_t)s);
    uint32_t rowc = b * 512u + pc;
    uint32_t rowz = b * 512u + pz;

    // negative rows: set j, row slot lm (same stream as round 8)
    uint32_t nrowAll[8];
    #pragma unroll
    for (int j = 0; j < 8; j++) {
        uint64_t x = sm64(((uint64_t)term << 40) +
                          (uint64_t)gidx * 128u + (uint64_t)(j * 16 + lm));
        nrowAll[j] = rowz_of((uint32_t)(x >> 32) % (uint32_t)T, dim, S, s);
    }

    uint16_t* nbw = nbuf[wv];
    const int gl = lane & 31, ghi = lane >> 5;
    const int wbase = ghi * 256 + gl * 8;         // u16; +i*512 per inst

    uint4 stg[2][8];
    h8 af[8];

    // issue: load set rows (row index from shfl of rowv) 2-segments/inst
    #define ISSUE(buf, rowv, base) { \
        _Pragma("unroll") \
        for (int i = 0; i < 8; i++) { \
            int rho = 2 * i + ghi; \
            uint32_t rr = (uint32_t)__shfl((int)(rowv), rho, 64); \
            uint32_t gc = (uint32_t)(gl ^ (rho & 7)); \
            stg[buf][i] = *(const uint4*)((base) + (size_t)rr * 256 + gc * 8); \
        } }
    #define WRITE(buf) { \
        _Pragma("unroll") \
        for (int i = 0; i < 8; i++) \
            *(uint4*)(nbw + wbase + i * 512) = stg[buf][i]; }
    // fragment read: (row lm, chunk ks*4+lq), XOR-swizzled position
    #define RDFRAG(ks) (*(const h8*)(nbw + lm * 256 + ((((ks) * 4 + lq) ^ (lm & 7)) << 3)))

    ISSUE(0, rowc, cTh);        // set 0: ctx
    ISSUE(1, rowz, ZW);         // set 1: pos

    // consume ctx -> A fragments
    WRITE(0);
    #pragma unroll
    for (int ks = 0; ks < 8; ks++) af[ks] = RDFRAG(ks);
    ISSUE(0, nrowAll[0], ZW);

    // consume pos -> accp
    WRITE(1);
    f32x4 accp = (f32x4){0.f, 0.f, 0.f, 0.f};
    #pragma unroll
    for (int ks = 0; ks < 8; ks++)
        accp = __builtin_amdgcn_mfma_f32_16x16x32_f16(af[ks], RDFRAG(ks), accp, 0, 0, 0);
    ISSUE(1, nrowAll[1], ZW);

    float* Sb = sbuf[wv];
    #pragma unroll
    for (int jj = 0; jj < 8; jj++) {
        WRITE(jj & 1);
        if (jj < 6) ISSUE(jj & 1, nrowAll[jj + 2], ZW);
        f32x4 accn = (f32x4){0.f, 0.f, 0.f, 0.f};
        #pragma unroll
        for (int ks = 0; ks < 8; ks++)
            accn = __builtin_amdgcn_mfma_f32_16x16x32_f16(af[ks], RDFRAG(ks), accn, 0, 0, 0);
        // positions 2jj,2jj+1 use set jj: lanes lq==jj>>1, regs (jj&1)*2,+1
        const int rr0 = (jj & 1) * 2;
        if (lq == (jj >> 1)) {
            Sb[(lq * 4 + rr0) * 17 + lm]     = accn[rr0];
            Sb[(lq * 4 + rr0 + 1) * 17 + lm] = accn[rr0 + 1];
        }
    }
    #undef ISSUE
    #undef WRITE
    #undef RDFRAG

    if ((lm >> 2) == lq) Sb[272 + lm] = accp[lm & 3];

    // softmax-NLL for position p = lm (4x redundant across lq)
    float dpos = Sb[272 + lm];
    float mx = dpos;
    float scn[16];
    #pragma unroll
    for (int n = 0; n < 16; n++) { scn[n] = Sb[lm * 17 + n]; mx = fmaxf(mx, scn[n]); }
    float e0 = __expf(dpos - mx), sum = e0;
    #pragma unroll
    for (int n = 0; n < 16; n++) sum += __expf(scn[n] - mx);
    float nll = -__logf(e0 / sum + EPSL);

    int mok = (ign[rowc] + ign[rowz]) == 0;
    float v = mok ? nll : 0.f;
    float cm = mok ? 1.f : 0.f;
    #pragma unroll
    for (int st = 1; st < 64; st <<= 1) {
        v  += __shfl_xor(v, st, 64);
        cm += __shfl_xor(cm, st, 64);
    }
    if (lane == 0) { wsum[wv] = v * 0.25f; wcnt[wv] = cm * 0.25f; }
    __syncthreads();
    if (t == 0) {
        float sv = wsum[0] + wsum[1] + wsum[2] + wsum[3];
        float cv = wcnt[0] + wcnt[1] + wcnt[2] + wcnt[3];
        int slot = blockIdx.x & 63;
        atomicAdd(&sums_s[term * 64 + slot], sv);
        atomicAdd(&cnts_s[term * 64 + slot], (int)(cv + 0.5f));
    }
}

__global__ void k_final(const float* __restrict__ sums_s, const int* __restrict__ cnts_s,
                        float* __restrict__ out) {
    __shared__ float ratio[18];
    int t = threadIdx.x;
    if (t < 18) {
        float sv = 0.f; int cv = 0;
        #pragma unroll 8
        for (int i = 0; i < 64; i++) { sv += sums_s[t * 64 + i]; cv += cnts_s[t * 64 + i]; }
        ratio[t] = sv / (float)cv;
    }
    __syncthreads();
    if (t == 0) {
        float tot = 0.f;
        #pragma unroll
        for (int i = 0; i < 18; i++) tot += ratio[i];
        out[0] = tot / 18.f;
    }
}

// ---------------- launch ----------------
extern "C" void kernel_launch(void* const* d_in, const int* in_sizes, int n_in,
                              void* d_out, int out_size, void* d_ws, size_t ws_size,
                              hipStream_t stream) {
    const float* z   = (const float*)d_in[0];
    const float* c   = (const float*)d_in[1];
    const int*   ign = (const int*)d_in[2];
    const float* Wk  = (const float*)d_in[3];

    float* sums_s = (float*)d_ws;                           // 18*64 floats
    int*   cnts_s = (int*)((char*)d_ws + 4608);             // 18*64 ints
    uint16_t* zh  = (uint16_t*)((char*)d_ws + 65536);       // 8 MiB row-major fp16
    uint16_t* cTh = zh  + (size_t)16384 * 256;              // 8 MiB row-major fp16
    uint16_t* Whf = cTh + (size_t)16384 * 256;              // 768 KiB B-frag order
    uint16_t* ZWh = Whf + (size_t)6 * 65536;                // 48 MiB row-major fp16

    hipLaunchKernelGGL(k_init, dim3(5), dim3(256), 0, stream, sums_s, cnts_s);
    hipLaunchKernelGGL(k_prep, dim3(8, 8, 64), dim3(256), 0, stream, z, c, zh, cTh);
    hipLaunchKernelGGL(k_castw, dim3(192), dim3(256), 0, stream, Wk, Whf);
    hipLaunchKernelGGL(k_gemm, dim3(128, 6), dim3(256), 0, stream, zh, Whf, ZWh);
    hipLaunchKernelGGL(k_score, dim3(2016), dim3(256), 0, stream, ZWh, cTh, ign, sums_s, cnts_s);
    hipLaunchKernelGGL(k_final, dim3(1), dim3(64), 0, stream, sums_s, cnts_s, (float*)d_out);
}

// Round 10
// 234.373 us; speedup vs baseline: 1.3958x; 1.3958x over previous
//
#include <hip/hip_runtime.h>
#include <stdint.h>

#define EPSL 1e-11f

typedef _Float16 h2 __attribute__((ext_vector_type(2)));
typedef _Float16 h8 __attribute__((ext_vector_type(8)));
typedef __attribute__((ext_vector_type(4))) float f32x4;
typedef __attribute__((ext_vector_type(16))) float f32x16;

// ---------------- helpers ----------------
__device__ __forceinline__ uint32_t pk2h(float a, float b) {
    union { h2 h; uint32_t u; } t;
    t.h = (h2){ (_Float16)a, (_Float16)b };
    return t.u;
}
__device__ __forceinline__ uint16_t f2h(float a) {
    union { _Float16 h; uint16_t u; } t; t.h = (_Float16)a; return t.u;
}

__device__ __forceinline__ uint64_t sm64(uint64_t x) {
    x += 0x9E3779B97F4A7C15ULL;
    x = (x ^ (x >> 30)) * 0xBF58476D1CE4E5B9ULL;
    x = (x ^ (x >> 27)) * 0x94D049BB133111EBULL;
    return x ^ (x >> 31);
}

__device__ __forceinline__ uint32_t rowz_of(uint32_t f, int dim, int S, int s) {
    uint32_t b = f & 31u;
    uint32_t r = f >> 5;
    uint32_t d, h, w;
    if (dim == 0) {
        w = r & 7u; h = (r >> 3) & 7u; d = (r >> 6) + (uint32_t)s;
    } else if (dim == 1) {
        w = r & 7u; uint32_t q = r >> 3;
        h = q % (uint32_t)S + (uint32_t)s; d = q / (uint32_t)S;
    } else {
        w = r % (uint32_t)S + (uint32_t)s; uint32_t q = r / (uint32_t)S;
        h = q & 7u; d = q >> 3;
    }
    return b * 512u + d * 64u + h * 8u + w;
}

// ---------------- kernels ----------------
__global__ void k_init(float* sums_s, int* cnts_s) {
    int t = blockIdx.x * 256 + threadIdx.x;
    if (t < 1152) { sums_s[t] = 0.f; cnts_s[t] = 0; }
}

// Transpose+cast to fp16, ROW-MAJOR [row=b*512+p][ch] for both z and c.
__global__ __launch_bounds__(256) void k_prep(const float* __restrict__ z,
                                              const float* __restrict__ c,
                                              uint16_t* __restrict__ zh,
                                              uint16_t* __restrict__ cTh) {
    __shared__ float tile[32][65];
    const int t = threadIdx.x;
    const int b = blockIdx.z & 31, isC = blockIdx.z >> 5;
    const float* src = (isC ? c : z) + (size_t)b * 131072;
    const int p0 = blockIdx.x * 64, ch0 = blockIdx.y * 32;
    const int pl = t & 63, cl0 = t >> 6;
    #pragma unroll
    for (int i = 0; i < 8; i++)
        tile[cl0 + i * 4][pl] = src[(ch0 + cl0 + i * 4) * 512 + p0 + pl];
    __syncthreads();
    const int ml = t >> 2, ck = (t & 3) * 8;
    uint4 o;
    o.x = pk2h(tile[ck + 0][ml], tile[ck + 1][ml]);
    o.y = pk2h(tile[ck + 2][ml], tile[ck + 3][ml]);
    o.z = pk2h(tile[ck + 4][ml], tile[ck + 5][ml]);
    o.w = pk2h(tile[ck + 6][ml], tile[ck + 7][ml]);
    uint16_t* dst = isC ? cTh : zh;
    *(uint4*)(dst + (size_t)(b * 512 + p0 + ml) * 256 + ch0 + ck) = o;
}

// W [kk][o][c] f32 -> Whf fp16, 32x32x16 B-fragment order
__global__ __launch_bounds__(256) void k_castw(const float* __restrict__ W,
                                               uint16_t* __restrict__ Whf) {
    const int gid = blockIdx.x * 4 + (threadIdx.x >> 6);
    const int lane = threadIdx.x & 63;
    const int kk = gid >> 7, rem = gid & 127;
    const int ks2 = rem >> 3, ot = rem & 7;
    const int o = ot * 32 + (lane & 31);
    const int cc = ks2 * 16 + (lane >> 5) * 8;
    const float* src = W + ((size_t)kk * 256 + o) * 256 + cc;
    float4 v0 = *(const float4*)src;
    float4 v1 = *(const float4*)(src + 4);
    uint4 out = make_uint4(pk2h(v0.x, v0.y), pk2h(v0.z, v0.w),
                           pk2h(v1.x, v1.y), pk2h(v1.z, v1.w));
    *(uint4*)(Whf + (size_t)gid * 512 + lane * 8) = out;
}

// ZWh[kk][m][o] via 32x32x16 MFMA (unchanged from round 7)
__global__ __launch_bounds__(256, 2) void k_gemm(const uint16_t* __restrict__ zh,
                                                 const uint16_t* __restrict__ Whf,
                                                 uint16_t* __restrict__ ZWh) {
    __shared__ uint16_t Bbuf[2][4096];
    __shared__ uint16_t Cbuf[4][4096];
    const int kk = blockIdx.y;
    const int t = threadIdx.x, lane = t & 63, wv = t >> 6;
    const int m0 = blockIdx.x * 128 + wv * 32;
    const int col = lane & 31, hl = lane >> 5;
    const uint16_t* W32 = Whf + (size_t)kk * 65536;
    const uint16_t* A0 = zh + (size_t)(m0 + col) * 256 + hl * 8;

    f32x16 acc[8];
    #pragma unroll
    for (int i = 0; i < 8; i++)
        #pragma unroll
        for (int jj = 0; jj < 16; jj++) acc[i][jj] = 0.f;

    {
        const uint16_t* src = W32 + t * 16;
        *(uint4*)(&Bbuf[0][t * 16]) = *(const uint4*)src;
        *(uint4*)(&Bbuf[0][t * 16 + 8]) = *(const uint4*)(src + 8);
    }
    __syncthreads();
    for (int ks2 = 0; ks2 < 16; ks2++) {
        if (ks2 < 15) {
            const uint16_t* src = W32 + (size_t)(ks2 + 1) * 4096 + t * 16;
            uint16_t* db = Bbuf[(ks2 + 1) & 1];
            *(uint4*)(&db[t * 16]) = *(const uint4*)src;
            *(uint4*)(&db[t * 16 + 8]) = *(const uint4*)(src + 8);
        }
        h8 a = *(const h8*)(A0 + ks2 * 16);
        const uint16_t* Bb = Bbuf[ks2 & 1];
        #pragma unroll
        for (int ot = 0; ot < 8; ot++) {
            h8 bv = *(const h8*)(&Bb[ot * 512 + lane * 8]);
            acc[ot] = __builtin_amdgcn_mfma_f32_32x32x16_f16(a, bv, acc[ot], 0, 0, 0);
        }
        __syncthreads();
    }

    uint16_t* Lb = Cbuf[wv];
    uint16_t* dstbase = ZWh + ((size_t)kk * 16384 + m0) * 256;
    #pragma unroll
    for (int hh = 0; hh < 2; hh++) {
        #pragma unroll
        for (int ot = 0; ot < 8; ot++)
            #pragma unroll
            for (int rg = 0; rg < 8; rg++) {
                int reg = hh * 8 + rg;
                int row = (reg & 3) + 8 * (reg >> 2) + 4 * hl;
                Lb[(row - hh * 16) * 256 + ot * 32 + col] = f2h(acc[ot][reg]);
            }
        const uint4* Lr = (const uint4*)Lb;
        uint4* dst = (uint4*)(dstbase + hh * 16 * 256);
        #pragma unroll
        for (int i = 0; i < 8; i++)
            dst[i * 64 + lane] = Lr[i * 64 + lane];
    }
}

// Score v10: segment-minimal staging (r9 layout/numerics) with the pipeline
// fully hand-unrolled into two NAMED register banks s0/s1 — every array index
// is a literal, so nothing can demote to scratch (r9's 552 MB WRITE_SIZE bug).
// One wave = 16 positions (same b, consecutive r). Sets: ctx, pos, 8 neg sets
// (positions 2j,2j+1 use set j). Per set: 8 insts x 2 row-segments -> single
// 8 KB LDS buffer/wave (in-order LDS), XOR bank swizzle.
__global__ __launch_bounds__(256, 3) void k_score(const uint16_t* __restrict__ ZWh,
                                                  const uint16_t* __restrict__ cTh,
                                                  const int* __restrict__ ign,
                                                  float* sums_s, int* cnts_s) {
    __shared__ uint16_t nbuf[4][4096];      // 4 waves x 8 KB
    __shared__ float sbuf[4][288];
    __shared__ float wsum[4], wcnt[4];
    int bid = blockIdx.x;
    int kk = 0, cum = 0;
    for (;;) { int nb = 96 * (6 - kk); if (bid < cum + nb) break; cum += nb; kk++; }
    const int S = 6 - kk, T = S * 2048, s = kk + 2;
    const uint16_t* ZW = ZWh + (size_t)kk * 16384 * 256;

    const int local = bid - cum;
    const int dim = local / (32 * S);
    const int loc2 = local - dim * 32 * S;
    const int term = dim * 6 + kk;

    const int t = threadIdx.x, lane = t & 63, wv = t >> 6;
    const int lm = lane & 15, lq = lane >> 4;
    const uint32_t gidx = (uint32_t)(loc2 * 4 + wv);
    const uint32_t b = gidx & 31u;
    const uint32_t rb = gidx >> 5;
    const uint32_t r = rb * 16u + (uint32_t)lm;   // row slot lm's position

    uint32_t d, h, w;
    if (dim == 0)      { w = r & 7u; h = (r >> 3) & 7u; d = r >> 6; }
    else if (dim == 1) { w = r & 7u; uint32_t qq = r >> 3; h = qq % (uint32_t)S; d = qq / (uint32_t)S; }
    else               { w = r % (uint32_t)S; uint32_t qq = r / (uint32_t)S; h = qq & 7u; d = qq >> 3; }
    uint32_t pc = d * 64u + h * 8u + w;
    uint32_t pz = pc + (dim == 0 ? (uint32_t)s * 64u : dim == 1 ? (uint32_t)s * 8u : (uint32_t)s);
    uint32_t rowc = b * 512u + pc;
    uint32_t rowz = b * 512u + pz;

    // negative rows: set j, row slot lm (same stream as rounds 8/9)
    uint32_t nrowAll[8];
    #pragma unroll
    for (int j = 0; j < 8; j++) {
        uint64_t x = sm64(((uint64_t)term << 40) +
                          (uint64_t)gidx * 128u + (uint64_t)(j * 16 + lm));
        nrowAll[j] = rowz_of((uint32_t)(x >> 32) % (uint32_t)T, dim, S, s);
    }

    uint16_t* nbw = nbuf[wv];
    const int gl = lane & 31, ghi = lane >> 5;
    const int wbase = ghi * 256 + gl * 8;         // u16; +i*512 per inst

    uint4 s0[8], s1[8];                            // two named staging banks
    h8 af[8];

    // load a set: inst i covers rows 2i,2i+1 full-width (2 segments/inst);
    // XOR bank swizzle on the global chunk index
    #define ISSUE0(rowv, base) { _Pragma("unroll") \
        for (int i_ = 0; i_ < 8; i_++) { \
            int rho_ = 2 * i_ + ghi; \
            uint32_t rr_ = (uint32_t)__shfl((int)(rowv), rho_, 64); \
            s0[i_] = *(const uint4*)((base) + (size_t)rr_ * 256 + (uint32_t)(gl ^ (rho_ & 7)) * 8); \
        } }
    #define ISSUE1(rowv, base) { _Pragma("unroll") \
        for (int i_ = 0; i_ < 8; i_++) { \
            int rho_ = 2 * i_ + ghi; \
            uint32_t rr_ = (uint32_t)__shfl((int)(rowv), rho_, 64); \
            s1[i_] = *(const uint4*)((base) + (size_t)rr_ * 256 + (uint32_t)(gl ^ (rho_ & 7)) * 8); \
        } }
    #define WRITE0() { _Pragma("unroll") \
        for (int i_ = 0; i_ < 8; i_++) *(uint4*)(nbw + wbase + i_ * 512) = s0[i_]; }
    #define WRITE1() { _Pragma("unroll") \
        for (int i_ = 0; i_ < 8; i_++) *(uint4*)(nbw + wbase + i_ * 512) = s1[i_]; }
    // fragment read: (row lm, chunk ks*4+lq), XOR-swizzled
    #define RDFRAG(ks) (*(const h8*)(nbw + lm * 256 + ((((ks) * 4 + lq) ^ (lm & 7)) << 3)))

    ISSUE0(rowc, cTh);          // ctx set
    ISSUE1(rowz, ZW);           // pos set

    WRITE0();                   // ctx -> LDS
    #pragma unroll
    for (int ks = 0; ks < 8; ks++) af[ks] = RDFRAG(ks);
    ISSUE0(nrowAll[0], ZW);     // neg set 0

    WRITE1();                   // pos -> LDS
    f32x4 accp = (f32x4){0.f, 0.f, 0.f, 0.f};
    #pragma unroll
    for (int ks = 0; ks < 8; ks++)
        accp = __builtin_amdgcn_mfma_f32_16x16x32_f16(af[ks], RDFRAG(ks), accp, 0, 0, 0);
    ISSUE1(nrowAll[1], ZW);     // neg set 1

    float* Sb = sbuf[wv];

    #define NSTEP_BODY(jj) { \
        f32x4 accn = (f32x4){0.f, 0.f, 0.f, 0.f}; \
        _Pragma("unroll") \
        for (int ks = 0; ks < 8; ks++) \
            accn = __builtin_amdgcn_mfma_f32_16x16x32_f16(af[ks], RDFRAG(ks), accn, 0, 0, 0); \
        const int rr0_ = ((jj) & 1) * 2; \
        if (lq == ((jj) >> 1)) { \
            Sb[(lq * 4 + rr0_) * 17 + lm]     = accn[rr0_]; \
            Sb[(lq * 4 + rr0_ + 1) * 17 + lm] = accn[rr0_ + 1]; \
        } }

    { WRITE0(); ISSUE0(nrowAll[2], ZW); NSTEP_BODY(0) }
    { WRITE1(); ISSUE1(nrowAll[3], ZW); NSTEP_BODY(1) }
    { WRITE0(); ISSUE0(nrowAll[4], ZW); NSTEP_BODY(2) }
    { WRITE1(); ISSUE1(nrowAll[5], ZW); NSTEP_BODY(3) }
    { WRITE0(); ISSUE0(nrowAll[6], ZW); NSTEP_BODY(4) }
    { WRITE1(); ISSUE1(nrowAll[7], ZW); NSTEP_BODY(5) }
    { WRITE0(); NSTEP_BODY(6) }
    { WRITE1(); NSTEP_BODY(7) }

    #undef ISSUE0
    #undef ISSUE1
    #undef WRITE0
    #undef WRITE1
    #undef RDFRAG
    #undef NSTEP_BODY

    if ((lm >> 2) == lq) Sb[272 + lm] = accp[lm & 3];

    // softmax-NLL for position p = lm (4x redundant across lq)
    float dpos = Sb[272 + lm];
    float mx = dpos;
    float scn[16];
    #pragma unroll
    for (int n = 0; n < 16; n++) { scn[n] = Sb[lm * 17 + n]; mx = fmaxf(mx, scn[n]); }
    float e0 = __expf(dpos - mx), sum = e0;
    #pragma unroll
    for (int n = 0; n < 16; n++) sum += __expf(scn[n] - mx);
    float nll = -__logf(e0 / sum + EPSL);

    int mok = (ign[rowc] + ign[rowz]) == 0;
    float v = mok ? nll : 0.f;
    float cm = mok ? 1.f : 0.f;
    #pragma unroll
    for (int st = 1; st < 64; st <<= 1) {
        v  += __shfl_xor(v, st, 64);
        cm += __shfl_xor(cm, st, 64);
    }
    if (lane == 0) { wsum[wv] = v * 0.25f; wcnt[wv] = cm * 0.25f; }
    __syncthreads();
    if (t == 0) {
        float sv = wsum[0] + wsum[1] + wsum[2] + wsum[3];
        float cv = wcnt[0] + wcnt[1] + wcnt[2] + wcnt[3];
        int slot = blockIdx.x & 63;
        atomicAdd(&sums_s[term * 64 + slot], sv);
        atomicAdd(&cnts_s[term * 64 + slot], (int)(cv + 0.5f));
    }
}

__global__ void k_final(const float* __restrict__ sums_s, const int* __restrict__ cnts_s,
                        float* __restrict__ out) {
    __shared__ float ratio[18];
    int t = threadIdx.x;
    if (t < 18) {
        float sv = 0.f; int cv = 0;
        #pragma unroll 8
        for (int i = 0; i < 64; i++) { sv += sums_s[t * 64 + i]; cv += cnts_s[t * 64 + i]; }
        ratio[t] = sv / (float)cv;
    }
    __syncthreads();
    if (t == 0) {
        float tot = 0.f;
        #pragma unroll
        for (int i = 0; i < 18; i++) tot += ratio[i];
        out[0] = tot / 18.f;
    }
}

// ---------------- launch ----------------
extern "C" void kernel_launch(void* const* d_in, const int* in_sizes, int n_in,
                              void* d_out, int out_size, void* d_ws, size_t ws_size,
                              hipStream_t stream) {
    const float* z   = (const float*)d_in[0];
    const float* c   = (const float*)d_in[1];
    const int*   ign = (const int*)d_in[2];
    const float* Wk  = (const float*)d_in[3];

    float* sums_s = (float*)d_ws;                           // 18*64 floats
    int*   cnts_s = (int*)((char*)d_ws + 4608);             // 18*64 ints
    uint16_t* zh  = (uint16_t*)((char*)d_ws + 65536);       // 8 MiB row-major fp16
    uint16_t* cTh = zh  + (size_t)16384 * 256;              // 8 MiB row-major fp16
    uint16_t* Whf = cTh + (size_t)16384 * 256;              // 768 KiB B-frag order
    uint16_t* ZWh = Whf + (size_t)6 * 65536;                // 48 MiB row-major fp16

    hipLaunchKernelGGL(k_init, dim3(5), dim3(256), 0, stream, sums_s, cnts_s);
    hipLaunchKernelGGL(k_prep, dim3(8, 8, 64), dim3(256), 0, stream, z, c, zh, cTh);
    hipLaunchKernelGGL(k_castw, dim3(192), dim3(256), 0, stream, Wk, Whf);
    hipLaunchKernelGGL(k_gemm, dim3(128, 6), dim3(256), 0, stream, zh, Whf, ZWh);
    hipLaunchKernelGGL(k_score, dim3(2016), dim3(256), 0, stream, ZWh, cTh, ign, sums_s, cnts_s);
    hipLaunchKernelGGL(k_final, dim3(1), dim3(64), 0, stream, sums_s, cnts_s, (float*)d_out);
}

// Round 11
// 180.734 us; speedup vs baseline: 1.8100x; 1.2968x over previous
//
#include <hip/hip_runtime.h>
#include <stdint.h>

#define EPSL 1e-11f

typedef _Float16 h2 __attribute__((ext_vector_type(2)));
typedef _Float16 h8 __attribute__((ext_vector_type(8)));
typedef __attribute__((ext_vector_type(4))) float f32x4;
typedef __attribute__((ext_vector_type(16))) float f32x16;

// ---------------- helpers ----------------
__device__ __forceinline__ uint32_t pk2h(float a, float b) {
    union { h2 h; uint32_t u; } t;
    t.h = (h2){ (_Float16)a, (_Float16)b };
    return t.u;
}
__device__ __forceinline__ uint16_t f2h(float a) {
    union { _Float16 h; uint16_t u; } t; t.h = (_Float16)a; return t.u;
}

__device__ __forceinline__ uint64_t sm64(uint64_t x) {
    x += 0x9E3779B97F4A7C15ULL;
    x = (x ^ (x >> 30)) * 0xBF58476D1CE4E5B9ULL;
    x = (x ^ (x >> 27)) * 0x94D049BB133111EBULL;
    return x ^ (x >> 31);
}

__device__ __forceinline__ uint32_t rowz_of(uint32_t f, int dim, int S, int s) {
    uint32_t b = f & 31u;
    uint32_t r = f >> 5;
    uint32_t d, h, w;
    if (dim == 0) {
        w = r & 7u; h = (r >> 3) & 7u; d = (r >> 6) + (uint32_t)s;
    } else if (dim == 1) {
        w = r & 7u; uint32_t q = r >> 3;
        h = q % (uint32_t)S + (uint32_t)s; d = q / (uint32_t)S;
    } else {
        w = r % (uint32_t)S + (uint32_t)s; uint32_t q = r / (uint32_t)S;
        h = q & 7u; d = q >> 3;
    }
    return b * 512u + d * 64u + h * 8u + w;
}

// ---------------- kernels ----------------
__global__ void k_init(float* sums_s, int* cnts_s) {
    int t = blockIdx.x * 256 + threadIdx.x;
    if (t < 1152) { sums_s[t] = 0.f; cnts_s[t] = 0; }
}

// Transpose+cast to fp16, ROW-MAJOR [row=b*512+p][ch] for both z and c.
__global__ __launch_bounds__(256) void k_prep(const float* __restrict__ z,
                                              const float* __restrict__ c,
                                              uint16_t* __restrict__ zh,
                                              uint16_t* __restrict__ cTh) {
    __shared__ float tile[32][65];
    const int t = threadIdx.x;
    const int b = blockIdx.z & 31, isC = blockIdx.z >> 5;
    const float* src = (isC ? c : z) + (size_t)b * 131072;
    const int p0 = blockIdx.x * 64, ch0 = blockIdx.y * 32;
    const int pl = t & 63, cl0 = t >> 6;
    #pragma unroll
    for (int i = 0; i < 8; i++)
        tile[cl0 + i * 4][pl] = src[(ch0 + cl0 + i * 4) * 512 + p0 + pl];
    __syncthreads();
    const int ml = t >> 2, ck = (t & 3) * 8;
    uint4 o;
    o.x = pk2h(tile[ck + 0][ml], tile[ck + 1][ml]);
    o.y = pk2h(tile[ck + 2][ml], tile[ck + 3][ml]);
    o.z = pk2h(tile[ck + 4][ml], tile[ck + 5][ml]);
    o.w = pk2h(tile[ck + 6][ml], tile[ck + 7][ml]);
    uint16_t* dst = isC ? cTh : zh;
    *(uint4*)(dst + (size_t)(b * 512 + p0 + ml) * 256 + ch0 + ck) = o;
}

// W [kk][o][c] f32 -> Whf fp16, 32x32x16 B-fragment order
__global__ __launch_bounds__(256) void k_castw(const float* __restrict__ W,
                                               uint16_t* __restrict__ Whf) {
    const int gid = blockIdx.x * 4 + (threadIdx.x >> 6);
    const int lane = threadIdx.x & 63;
    const int kk = gid >> 7, rem = gid & 127;
    const int ks2 = rem >> 3, ot = rem & 7;
    const int o = ot * 32 + (lane & 31);
    const int cc = ks2 * 16 + (lane >> 5) * 8;
    const float* src = W + ((size_t)kk * 256 + o) * 256 + cc;
    float4 v0 = *(const float4*)src;
    float4 v1 = *(const float4*)(src + 4);
    uint4 out = make_uint4(pk2h(v0.x, v0.y), pk2h(v0.z, v0.w),
                           pk2h(v1.x, v1.y), pk2h(v1.z, v1.w));
    *(uint4*)(Whf + (size_t)gid * 512 + lane * 8) = out;
}

// ZWh[kk][m][o] via 32x32x16 MFMA (unchanged from round 7)
__global__ __launch_bounds__(256, 2) void k_gemm(const uint16_t* __restrict__ zh,
                                                 const uint16_t* __restrict__ Whf,
                                                 uint16_t* __restrict__ ZWh) {
    __shared__ uint16_t Bbuf[2][4096];
    __shared__ uint16_t Cbuf[4][4096];
    const int kk = blockIdx.y;
    const int t = threadIdx.x, lane = t & 63, wv = t >> 6;
    const int m0 = blockIdx.x * 128 + wv * 32;
    const int col = lane & 31, hl = lane >> 5;
    const uint16_t* W32 = Whf + (size_t)kk * 65536;
    const uint16_t* A0 = zh + (size_t)(m0 + col) * 256 + hl * 8;

    f32x16 acc[8];
    #pragma unroll
    for (int i = 0; i < 8; i++)
        #pragma unroll
        for (int jj = 0; jj < 16; jj++) acc[i][jj] = 0.f;

    {
        const uint16_t* src = W32 + t * 16;
        *(uint4*)(&Bbuf[0][t * 16]) = *(const uint4*)src;
        *(uint4*)(&Bbuf[0][t * 16 + 8]) = *(const uint4*)(src + 8);
    }
    __syncthreads();
    for (int ks2 = 0; ks2 < 16; ks2++) {
        if (ks2 < 15) {
            const uint16_t* src = W32 + (size_t)(ks2 + 1) * 4096 + t * 16;
            uint16_t* db = Bbuf[(ks2 + 1) & 1];
            *(uint4*)(&db[t * 16]) = *(const uint4*)src;
            *(uint4*)(&db[t * 16 + 8]) = *(const uint4*)(src + 8);
        }
        h8 a = *(const h8*)(A0 + ks2 * 16);
        const uint16_t* Bb = Bbuf[ks2 & 1];
        #pragma unroll
        for (int ot = 0; ot < 8; ot++) {
            h8 bv = *(const h8*)(&Bb[ot * 512 + lane * 8]);
            acc[ot] = __builtin_amdgcn_mfma_f32_32x32x16_f16(a, bv, acc[ot], 0, 0, 0);
        }
        __syncthreads();
    }

    uint16_t* Lb = Cbuf[wv];
    uint16_t* dstbase = ZWh + ((size_t)kk * 16384 + m0) * 256;
    #pragma unroll
    for (int hh = 0; hh < 2; hh++) {
        #pragma unroll
        for (int ot = 0; ot < 8; ot++)
            #pragma unroll
            for (int rg = 0; rg < 8; rg++) {
                int reg = hh * 8 + rg;
                int row = (reg & 3) + 8 * (reg >> 2) + 4 * hl;
                Lb[(row - hh * 16) * 256 + ot * 32 + col] = f2h(acc[ot][reg]);
            }
        const uint4* Lr = (const uint4*)Lb;
        uint4* dst = (uint4*)(dstbase + hh * 16 * 256);
        #pragma unroll
        for (int i = 0; i < 8; i++)
            dst[i * 64 + lane] = Lr[i * 64 + lane];
    }
}

// Score v11: staging via global_load_lds DMA — zero VGPR staging (r9/r10's
// scratch-spill bug is structurally impossible). One wave = 16 positions
// (same b, consecutive r). Sets: ctx, pos, 8 neg sets (positions 2j,2j+1 use
// set j). Per set: 8 DMA insts, inst i covers rows 2i,2i+1 (2 row-segments),
// LDS dest = base + lane*16 (row-major), XOR chunk swizzle applied on the
// GLOBAL address so fragment ds_read_b128 are 2-way (free). Single 8 KB
// buffer/wave; explicit vmcnt/lgkmcnt waits; TLP (4 blocks/CU) hides latency.
__global__ __launch_bounds__(256, 4) void k_score(const uint16_t* __restrict__ ZWh,
                                                  const uint16_t* __restrict__ cTh,
                                                  const int* __restrict__ ign,
                                                  float* sums_s, int* cnts_s) {
    __shared__ __align__(16) uint16_t nbuf[4][4096];   // 4 waves x 8 KB
    __shared__ float sbuf[4][288];
    __shared__ float wsum[4], wcnt[4];
    int bid = blockIdx.x;
    int kk = 0, cum = 0;
    for (;;) { int nb = 96 * (6 - kk); if (bid < cum + nb) break; cum += nb; kk++; }
    const int S = 6 - kk, T = S * 2048, s = kk + 2;
    const uint16_t* ZW = ZWh + (size_t)kk * 16384 * 256;

    const int local = bid - cum;
    const int dim = local / (32 * S);
    const int loc2 = local - dim * 32 * S;
    const int term = dim * 6 + kk;

    const int t = threadIdx.x, lane = t & 63, wv = t >> 6;
    const int lm = lane & 15, lq = lane >> 4;
    const int gl = lane & 31, ghi = lane >> 5;
    const uint32_t gidx = (uint32_t)(loc2 * 4 + wv);
    const uint32_t b = gidx & 31u;
    const uint32_t rb = gidx >> 5;
    const uint32_t r = rb * 16u + (uint32_t)lm;   // row slot lm's position

    uint32_t d, h, w;
    if (dim == 0)      { w = r & 7u; h = (r >> 3) & 7u; d = r >> 6; }
    else if (dim == 1) { w = r & 7u; uint32_t qq = r >> 3; h = qq % (uint32_t)S; d = qq / (uint32_t)S; }
    else               { w = r % (uint32_t)S; uint32_t qq = r / (uint32_t)S; h = qq & 7u; d = qq >> 3; }
    uint32_t pc = d * 64u + h * 8u + w;
    uint32_t pz = pc + (dim == 0 ? (uint32_t)s * 64u : dim == 1 ? (uint32_t)s * 8u : (uint32_t)s);
    uint32_t rowc = b * 512u + pc;
    uint32_t rowz = b * 512u + pz;

    // negative rows: set j, row slot lm (same stream as rounds 8-10)
    uint32_t nrowAll[8];
    #pragma unroll
    for (int j = 0; j < 8; j++) {
        uint64_t x = sm64(((uint64_t)term << 40) +
                          (uint64_t)gidx * 128u + (uint64_t)(j * 16 + lm));
        nrowAll[j] = rowz_of((uint32_t)(x >> 32) % (uint32_t)T, dim, S, s);
    }

    // mask loads issued early (drained by the first vmcnt(0))
    int mok = (ign[rowc] + ign[rowz]) == 0;

    uint16_t* nbw = nbuf[wv];

    // DMA one set (16 rows x 512 B): inst i covers rows 2i,2i+1.
    // global chunk = gl ^ (rowslot&7); LDS dest = nbw + i*1024B + lane*16B.
    #define STAGE(rowv, baseptr) { _Pragma("unroll") \
        for (int i_ = 0; i_ < 8; i_++) { \
            int rs_ = 2 * i_ + ghi; \
            uint32_t rr_ = (uint32_t)__shfl((int)(rowv), rs_, 64); \
            const uint16_t* g_ = (baseptr) + (size_t)rr_ * 256 + (uint32_t)((gl ^ (rs_ & 7)) * 8); \
            __builtin_amdgcn_global_load_lds( \
                (const __attribute__((address_space(1))) void*)g_, \
                (__attribute__((address_space(3))) void*)(nbw + i_ * 512), 16, 0, 0); \
        } }
    #define WAIT_VM()   asm volatile("s_waitcnt vmcnt(0)" ::: "memory")
    #define WAIT_LGKM() asm volatile("s_waitcnt lgkmcnt(0)" ::: "memory")
    // fragment read: row lm, global chunk ks*4+lq at swizzled position
    #define RDFRAG(ks) (*(const h8*)(nbw + lm * 256 + ((((ks) * 4 + lq) ^ (lm & 7)) * 8)))

    // set 0: ctx -> A fragments
    STAGE(rowc, cTh);
    WAIT_VM();
    h8 af[8];
    #pragma unroll
    for (int ks = 0; ks < 8; ks++) af[ks] = RDFRAG(ks);
    WAIT_LGKM();

    // set 1: pos -> accp
    STAGE(rowz, ZW);
    WAIT_VM();
    f32x4 accp = (f32x4){0.f, 0.f, 0.f, 0.f};
    #pragma unroll
    for (int ks = 0; ks < 8; ks++)
        accp = __builtin_amdgcn_mfma_f32_16x16x32_f16(af[ks], RDFRAG(ks), accp, 0, 0, 0);
    WAIT_LGKM();

    float* Sb = sbuf[wv];
    #pragma unroll
    for (int jj = 0; jj < 8; jj++) {
        STAGE(nrowAll[jj], ZW);
        WAIT_VM();
        f32x4 accn = (f32x4){0.f, 0.f, 0.f, 0.f};
        #pragma unroll
        for (int ks = 0; ks < 8; ks++)
            accn = __builtin_amdgcn_mfma_f32_16x16x32_f16(af[ks], RDFRAG(ks), accn, 0, 0, 0);
        WAIT_LGKM();
        // positions 2jj,2jj+1 use set jj: lanes lq==jj>>1, regs (jj&1)*2,+1
        const int rr0 = (jj & 1) * 2;
        if (lq == (jj >> 1)) {
            Sb[(lq * 4 + rr0) * 17 + lm]     = accn[rr0];
            Sb[(lq * 4 + rr0 + 1) * 17 + lm] = accn[rr0 + 1];
        }
    }
    #undef STAGE
    #undef WAIT_VM
    #undef WAIT_LGKM
    #undef RDFRAG

    if ((lm >> 2) == lq) Sb[272 + lm] = accp[lm & 3];

    // softmax-NLL for position p = lm (4x redundant across lq)
    float dpos = Sb[272 + lm];
    float mx = dpos;
    float scn[16];
    #pragma unroll
    for (int n = 0; n < 16; n++) { scn[n] = Sb[lm * 17 + n]; mx = fmaxf(mx, scn[n]); }
    float e0 = __expf(dpos - mx), sum = e0;
    #pragma unroll
    for (int n = 0; n < 16; n++) sum += __expf(scn[n] - mx);
    float nll = -__logf(e0 / sum + EPSL);

    float v = mok ? nll : 0.f;
    float cm = mok ? 1.f : 0.f;
    #pragma unroll
    for (int st = 1; st < 64; st <<= 1) {
        v  += __shfl_xor(v, st, 64);
        cm += __shfl_xor(cm, st, 64);
    }
    if (lane == 0) { wsum[wv] = v * 0.25f; wcnt[wv] = cm * 0.25f; }
    __syncthreads();
    if (t == 0) {
        float sv = wsum[0] + wsum[1] + wsum[2] + wsum[3];
        float cv = wcnt[0] + wcnt[1] + wcnt[2] + wcnt[3];
        int slot = blockIdx.x & 63;
        atomicAdd(&sums_s[term * 64 + slot], sv);
        atomicAdd(&cnts_s[term * 64 + slot], (int)(cv + 0.5f));
    }
}

__global__ void k_final(const float* __restrict__ sums_s, const int* __restrict__ cnts_s,
                        float* __restrict__ out) {
    __shared__ float ratio[18];
    int t = threadIdx.x;
    if (t < 18) {
        float sv = 0.f; int cv = 0;
        #pragma unroll 8
        for (int i = 0; i < 64; i++) { sv += sums_s[t * 64 + i]; cv += cnts_s[t * 64 + i]; }
        ratio[t] = sv / (float)cv;
    }
    __syncthreads();
    if (t == 0) {
        float tot = 0.f;
        #pragma unroll
        for (int i = 0; i < 18; i++) tot += ratio[i];
        out[0] = tot / 18.f;
    }
}

// ---------------- launch ----------------
extern "C" void kernel_launch(void* const* d_in, const int* in_sizes, int n_in,
                              void* d_out, int out_size, void* d_ws, size_t ws_size,
                              hipStream_t stream) {
    const float* z   = (const float*)d_in[0];
    const float* c   = (const float*)d_in[1];
    const int*   ign = (const int*)d_in[2];
    const float* Wk  = (const float*)d_in[3];

    float* sums_s = (float*)d_ws;                           // 18*64 floats
    int*   cnts_s = (int*)((char*)d_ws + 4608);             // 18*64 ints
    uint16_t* zh  = (uint16_t*)((char*)d_ws + 65536);       // 8 MiB row-major fp16
    uint16_t* cTh = zh  + (size_t)16384 * 256;              // 8 MiB row-major fp16
    uint16_t* Whf = cTh + (size_t)16384 * 256;              // 768 KiB B-frag order
    uint16_t* ZWh = Whf + (size_t)6 * 65536;                // 48 MiB row-major fp16

    hipLaunchKernelGGL(k_init, dim3(5), dim3(256), 0, stream, sums_s, cnts_s);
    hipLaunchKernelGGL(k_prep, dim3(8, 8, 64), dim3(256), 0, stream, z, c, zh, cTh);
    hipLaunchKernelGGL(k_castw, dim3(192), dim3(256), 0, stream, Wk, Whf);
    hipLaunchKernelGGL(k_gemm, dim3(128, 6), dim3(256), 0, stream, zh, Whf, ZWh);
    hipLaunchKernelGGL(k_score, dim3(2016), dim3(256), 0, stream, ZWh, cTh, ign, sums_s, cnts_s);
    hipLaunchKernelGGL(k_final, dim3(1), dim3(64), 0, stream, sums_s, cnts_s, (float*)d_out);
}